// Round 1
// baseline (404.865 us; speedup 1.0000x reference)
//
#include <hip/hip_runtime.h>
#include <hip/hip_bf16.h>
#include <cstdint>
#include <cstddef>

constexpr int BATCH = 2;
constexpr int C_IN  = 64;
constexpr int CK    = 1024;   // C_IN * N_FILTERS
constexpr int C_OUT = 256;

// ---------------- CSR build ----------------
__global__ void hist_kernel(const int* __restrict__ dst, int* __restrict__ counts, int E) {
    int e = blockIdx.x * blockDim.x + threadIdx.x;
    if (e < E) atomicAdd(&counts[dst[e]], 1);
}

// single-block exclusive scan over n counts -> offsets[0..n]
__global__ void scan_kernel(const int* __restrict__ counts, int* __restrict__ offsets, int n) {
    __shared__ int s[1024];
    __shared__ int carry_s;
    const int t = threadIdx.x;
    if (t == 0) carry_s = 0;
    __syncthreads();
    const int nchunk = (n + 1023) >> 10;
    for (int c = 0; c < nchunk; ++c) {
        const int idx = (c << 10) + t;
        const int v = (idx < n) ? counts[idx] : 0;
        int acc = v;
        s[t] = v;
        __syncthreads();
        #pragma unroll
        for (int off = 1; off < 1024; off <<= 1) {
            int x = (t >= off) ? s[t - off] : 0;
            __syncthreads();
            acc += x;
            s[t] = acc;
            __syncthreads();
        }
        const int carry = carry_s;                 // uniform read
        if (idx < n) offsets[idx] = carry + acc - v;
        __syncthreads();                            // everyone read carry_s
        if (t == 1023) carry_s = carry + s[1023];   // add chunk total
        __syncthreads();
    }
    if (t == 0) offsets[n] = carry_s;
}

__global__ void scatter_kernel(const int* __restrict__ dst, const int* __restrict__ offsets,
                               int* __restrict__ cursors, int* __restrict__ sorted, int E) {
    int e = blockIdx.x * blockDim.x + threadIdx.x;
    if (e < E) {
        const int d = dst[e];
        const int p = atomicAdd(&cursors[d], 1);
        sorted[offsets[d] + p] = e;
    }
}

// ---------------- per-node edge aggregation (CSR gather, no atomics) ----------------
// block = 256 threads handles one (b, n). Thread t owns k = t + 256*i, i=0..3.
// Note k & 63 == t & 63 for all i -> one feature value per thread.
__global__ __launch_bounds__(256)
void agg_kernel(const float* __restrict__ feats, const float* __restrict__ pos,
                const int* __restrict__ esrc, const int* __restrict__ sorted,
                const int* __restrict__ offsets,
                const float* __restrict__ W_dir, const float* __restrict__ b_dir,
                float* __restrict__ agg, int N) {
    const int n = blockIdx.x;
    const int b = blockIdx.y;
    const int t = threadIdx.x;
    const int c = t & 63;
    const float* posb   = pos   + (size_t)b * N * 3;
    const float* featsb = feats + (size_t)b * N * C_IN;

    const float px = posb[n * 3 + 0];
    const float py = posb[n * 3 + 1];
    const float pz = posb[n * 3 + 2];

    float wx[4], wy[4], wz[4], bb[4];
    #pragma unroll
    for (int i = 0; i < 4; ++i) {
        const int k = t + 256 * i;
        wx[i] = W_dir[k * 3 + 0];
        wy[i] = W_dir[k * 3 + 1];
        wz[i] = W_dir[k * 3 + 2];
        bb[i] = b_dir[k];
    }

    float acc[4] = {0.f, 0.f, 0.f, 0.f};
    const int beg = offsets[n];
    const int end = offsets[n + 1];
    for (int j = beg; j < end; ++j) {
        const int e = sorted[j];
        const int s = esrc[e];
        const float dx = posb[s * 3 + 0] - px;
        const float dy = posb[s * 3 + 1] - py;
        const float dz = posb[s * 3 + 2] - pz;
        const float f  = featsb[(size_t)s * C_IN + c];
        #pragma unroll
        for (int i = 0; i < 4; ++i) {
            const float a = fmaxf(dx * wx[i] + dy * wy[i] + dz * wz[i] + bb[i], 0.f);
            acc[i] += f * a;
        }
    }
    // self contribution: d = 0 -> relu(b_dir)
    const float fs = featsb[(size_t)n * C_IN + c];
    #pragma unroll
    for (int i = 0; i < 4; ++i) acc[i] += fs * fmaxf(bb[i], 0.f);

    float* dstp = agg + ((size_t)(b * N + n)) * CK + t;
    #pragma unroll
    for (int i = 0; i < 4; ++i) dstp[i * 256] = acc[i];
}

// ---------------- output GEMM: out[M,256] = relu(agg[M,1024] @ Wf^T + bf) ----------------
constexpr int MT = 64, NT = 128, KT = 32;

__global__ __launch_bounds__(256)
void gemm_kernel(const float* __restrict__ agg, const float* __restrict__ Wf,
                 const float* __restrict__ bf, float* __restrict__ out, int M) {
    __shared__ float a_s[KT][MT];   // transposed: [kk][row]  8 KB
    __shared__ float w_s[KT][NT];   // transposed: [kk][col] 16 KB
    const int t  = threadIdx.x;
    const int tx = t & 31;      // col group: 4 cols
    const int ty = t >> 5;      // row group: 8 rows
    const int r0 = blockIdx.x * MT;
    const int c0 = blockIdx.y * NT;

    float acc[8][4];
    #pragma unroll
    for (int i = 0; i < 8; ++i)
        #pragma unroll
        for (int j = 0; j < 4; ++j) acc[i][j] = 0.f;

    for (int k0 = 0; k0 < CK; k0 += KT) {
        // A tile: 64 rows x 32 k  (512 float4, 2 per thread)
        #pragma unroll
        for (int j = 0; j < 2; ++j) {
            const int lin = t + 256 * j;
            const int row = lin >> 3;
            const int kv  = lin & 7;
            float4 v = make_float4(0.f, 0.f, 0.f, 0.f);
            const int gr = r0 + row;
            if (gr < M) v = *reinterpret_cast<const float4*>(agg + (size_t)gr * CK + k0 + kv * 4);
            a_s[kv * 4 + 0][row] = v.x;
            a_s[kv * 4 + 1][row] = v.y;
            a_s[kv * 4 + 2][row] = v.z;
            a_s[kv * 4 + 3][row] = v.w;
        }
        // W tile: 128 cols x 32 k (1024 float4, 4 per thread)
        #pragma unroll
        for (int j = 0; j < 4; ++j) {
            const int lin = t + 256 * j;
            const int o   = lin >> 3;
            const int kv  = lin & 7;
            const float4 v = *reinterpret_cast<const float4*>(Wf + (size_t)(c0 + o) * CK + k0 + kv * 4);
            w_s[kv * 4 + 0][o] = v.x;
            w_s[kv * 4 + 1][o] = v.y;
            w_s[kv * 4 + 2][o] = v.z;
            w_s[kv * 4 + 3][o] = v.w;
        }
        __syncthreads();
        #pragma unroll
        for (int kk = 0; kk < KT; ++kk) {
            const float4 a0 = *reinterpret_cast<const float4*>(&a_s[kk][ty * 8]);
            const float4 a1 = *reinterpret_cast<const float4*>(&a_s[kk][ty * 8 + 4]);
            const float4 w  = *reinterpret_cast<const float4*>(&w_s[kk][tx * 4]);
            const float av[8] = {a0.x, a0.y, a0.z, a0.w, a1.x, a1.y, a1.z, a1.w};
            const float wv[4] = {w.x, w.y, w.z, w.w};
            #pragma unroll
            for (int i = 0; i < 8; ++i)
                #pragma unroll
                for (int j = 0; j < 4; ++j)
                    acc[i][j] += av[i] * wv[j];
        }
        __syncthreads();
    }

    #pragma unroll
    for (int i = 0; i < 8; ++i) {
        const int gr = r0 + ty * 8 + i;
        if (gr < M) {
            const int gc = c0 + tx * 4;
            float4 o4;
            o4.x = fmaxf(acc[i][0] + bf[gc + 0], 0.f);
            o4.y = fmaxf(acc[i][1] + bf[gc + 1], 0.f);
            o4.z = fmaxf(acc[i][2] + bf[gc + 2], 0.f);
            o4.w = fmaxf(acc[i][3] + bf[gc + 3], 0.f);
            *reinterpret_cast<float4*>(out + (size_t)gr * C_OUT + gc) = o4;
        }
    }
}

extern "C" void kernel_launch(void* const* d_in, const int* in_sizes, int n_in,
                              void* d_out, int out_size, void* d_ws, size_t ws_size,
                              hipStream_t stream) {
    const float* feats  = (const float*)d_in[0];
    const float* pos    = (const float*)d_in[1];
    const int*   esrc   = (const int*)d_in[2];
    const int*   edst   = (const int*)d_in[3];
    const float* W_dir  = (const float*)d_in[4];
    const float* b_dir  = (const float*)d_in[5];
    const float* W_feat = (const float*)d_in[6];
    const float* b_feat = (const float*)d_in[7];
    float* out = (float*)d_out;

    const int N = in_sizes[1] / (BATCH * 3);
    const int E = in_sizes[2];
    const int M = BATCH * N;

    char* ws = (char*)d_ws;
    size_t off = 0;
    auto alignup = [&](size_t a) { off = (off + a - 1) & ~(a - 1); };

    float* agg = (float*)(ws + off); off += (size_t)M * CK * sizeof(float);
    alignup(256);
    int* counts  = (int*)(ws + off); off += (size_t)N * sizeof(int);
    int* cursors = (int*)(ws + off); off += (size_t)N * sizeof(int);   // contiguous with counts
    alignup(256);
    int* offsets = (int*)(ws + off); off += (size_t)(N + 1) * sizeof(int);
    alignup(256);
    int* sorted  = (int*)(ws + off); off += (size_t)E * sizeof(int);

    hipMemsetAsync(counts, 0, (size_t)2 * N * sizeof(int), stream);  // counts + cursors
    hist_kernel<<<dim3((E + 255) / 256), dim3(256), 0, stream>>>(edst, counts, E);
    scan_kernel<<<dim3(1), dim3(1024), 0, stream>>>(counts, offsets, N);
    scatter_kernel<<<dim3((E + 255) / 256), dim3(256), 0, stream>>>(edst, offsets, cursors, sorted, E);
    agg_kernel<<<dim3(N, BATCH), dim3(256), 0, stream>>>(feats, pos, esrc, sorted, offsets,
                                                         W_dir, b_dir, agg, N);
    gemm_kernel<<<dim3((M + MT - 1) / MT, C_OUT / NT), dim3(256), 0, stream>>>(agg, W_feat, b_feat, out, M);
}

// Round 5
// 194.574 us; speedup vs baseline: 2.0808x; 2.0808x over previous
//
#include <hip/hip_runtime.h>
#include <hip/hip_bf16.h>
#include <cstdint>
#include <cstddef>

constexpr int BATCH = 2;
constexpr int C_IN  = 64;
constexpr int CK    = 1024;   // C_IN * N_FILTERS
constexpr int C_OUT = 256;

using bf16x8 = __attribute__((ext_vector_type(8))) short;
using f32x4  = __attribute__((ext_vector_type(4))) float;

#define GLOAD_LDS16(g, s) \
    __builtin_amdgcn_global_load_lds((const __attribute__((address_space(1))) void*)(g), \
                                     (__attribute__((address_space(3))) void*)(s), 16, 0, 0)

// ---------------- CSR build ----------------
__global__ void hist_kernel(const int* __restrict__ dst, int* __restrict__ counts, int E) {
    int e = blockIdx.x * blockDim.x + threadIdx.x;
    if (e < E) atomicAdd(&counts[dst[e]], 1);
}

// 1024-thread single-block exclusive scan via wave shuffles (2 barriers/chunk)
__global__ __launch_bounds__(1024)
void scan_kernel(const int* __restrict__ counts, int* __restrict__ offsets, int n) {
    __shared__ int wsum[16];
    __shared__ int carry_s;
    const int t = threadIdx.x;
    const int lane = t & 63;
    const int w = t >> 6;
    if (t == 0) carry_s = 0;
    __syncthreads();
    const int nch = (n + 1023) >> 10;
    for (int c = 0; c < nch; ++c) {
        const int idx = (c << 10) + t;
        const int v = (idx < n) ? counts[idx] : 0;
        // inclusive wave scan
        int x = v;
        #pragma unroll
        for (int off = 1; off < 64; off <<= 1) {
            int y = __shfl_up(x, off, 64);
            if (lane >= off) x += y;
        }
        if (lane == 63) wsum[w] = x;
        __syncthreads();
        int wpre = 0, total = 0;
        #pragma unroll
        for (int i = 0; i < 16; ++i) {
            const int s = wsum[i];
            if (i < w) wpre += s;
            total += s;
        }
        const int carry = carry_s;
        if (idx < n) offsets[idx] = carry + wpre + (x - v);   // exclusive
        __syncthreads();
        if (t == 0) carry_s = carry + total;
    }
    if (t == 0) offsets[n] = carry_s;   // t0 wrote carry_s itself; safe
}

// store SRC node id directly (removes one indirection from agg's inner loop)
__global__ void scatter_kernel(const int* __restrict__ dst, const int* __restrict__ src,
                               const int* __restrict__ offsets,
                               int* __restrict__ cursors, int* __restrict__ sorted_src, int E) {
    int e = blockIdx.x * blockDim.x + threadIdx.x;
    if (e < E) {
        const int d = dst[e];
        const int p = atomicAdd(&cursors[d], 1);
        sorted_src[offsets[d] + p] = src[e];
    }
}

// ---------------- per-node edge aggregation -> bf16 agg ----------------
// block = 256 threads per (b,n). Thread t owns k in {2t, 2t+1, 2t+512, 2t+513}:
// channel c = (2t)&63 (+1) -> one float2 feature load; stores are 4B/lane coalesced.
__global__ __launch_bounds__(256)
void agg_kernel(const float* __restrict__ feats, const float* __restrict__ pos,
                const int* __restrict__ sorted_src, const int* __restrict__ offsets,
                const float* __restrict__ W_dir, const float* __restrict__ b_dir,
                __hip_bfloat16* __restrict__ agg, int N) {
    const int n = blockIdx.x;
    const int b = blockIdx.y;
    const int t = threadIdx.x;
    const int c0 = (2 * t) & 63;
    const float* posb   = pos   + (size_t)b * N * 3;
    const float* featsb = feats + (size_t)b * N * C_IN;

    const float px = posb[n * 3 + 0];
    const float py = posb[n * 3 + 1];
    const float pz = posb[n * 3 + 2];

    float wx[4], wy[4], wz[4], bb[4];
    #pragma unroll
    for (int u = 0; u < 4; ++u) {                    // k = 2t + 512*(u>>1) + (u&1)
        const int k = 2 * t + 512 * (u >> 1) + (u & 1);
        wx[u] = W_dir[k * 3 + 0];
        wy[u] = W_dir[k * 3 + 1];
        wz[u] = W_dir[k * 3 + 2];
        bb[u] = b_dir[k];
    }

    float acc[4] = {0.f, 0.f, 0.f, 0.f};
    const int beg = offsets[n];
    const int end = offsets[n + 1];
    for (int j = beg; j < end; ++j) {
        const int s = sorted_src[j];
        const float dx = posb[s * 3 + 0] - px;
        const float dy = posb[s * 3 + 1] - py;
        const float dz = posb[s * 3 + 2] - pz;
        const float2 f = *reinterpret_cast<const float2*>(featsb + (size_t)s * C_IN + c0);
        #pragma unroll
        for (int u = 0; u < 4; ++u) {
            const float a = fmaxf(fmaf(dx, wx[u], fmaf(dy, wy[u], fmaf(dz, wz[u], bb[u]))), 0.f);
            acc[u] += ((u & 1) ? f.y : f.x) * a;
        }
    }
    const float2 fs = *reinterpret_cast<const float2*>(featsb + (size_t)n * C_IN + c0);
    #pragma unroll
    for (int u = 0; u < 4; ++u) acc[u] += ((u & 1) ? fs.y : fs.x) * fmaxf(bb[u], 0.f);

    __hip_bfloat16* dst = agg + (size_t)(b * (size_t)N + n) * CK;
    __hip_bfloat162 v01, v23;
    v01.x = __float2bfloat16(acc[0]); v01.y = __float2bfloat16(acc[1]);
    v23.x = __float2bfloat16(acc[2]); v23.y = __float2bfloat16(acc[3]);
    *reinterpret_cast<__hip_bfloat162*>(dst + 2 * t)       = v01;
    *reinterpret_cast<__hip_bfloat162*>(dst + 2 * t + 512) = v23;
}

// ---------------- W_feat f32 -> bf16 ----------------
__global__ __launch_bounds__(256)
void cvtw_kernel(const float* __restrict__ in, __hip_bfloat16* __restrict__ out) {
    const int i = (blockIdx.x * 256 + threadIdx.x) * 4;   // total 262144
    const float4 v = *reinterpret_cast<const float4*>(in + i);
    __hip_bfloat162 a, b;
    a.x = __float2bfloat16(v.x); a.y = __float2bfloat16(v.y);
    b.x = __float2bfloat16(v.z); b.y = __float2bfloat16(v.w);
    *reinterpret_cast<__hip_bfloat162*>(out + i)     = a;
    *reinterpret_cast<__hip_bfloat162*>(out + i + 2) = b;
}

// ---------------- MFMA GEMM: out[M,256] = relu(agg[M,1024](bf16) @ W^T(bf16) + bf) ----
// 128x128 tile, BK=64, 4 waves (2x2), global_load_lds + XOR-swizzled LDS (T2/rule21).
// LDS logical layout [row][64k] (128B/row); physical chunk = logical_chunk ^ (row&7).
__global__ __launch_bounds__(256)
void gemm_kernel(const __hip_bfloat16* __restrict__ agg, const __hip_bfloat16* __restrict__ W,
                 const float* __restrict__ bf, float* __restrict__ out, int M) {
    __shared__ __hip_bfloat16 As[128 * 64];
    __shared__ __hip_bfloat16 Bs[128 * 64];
    const int t    = threadIdx.x;
    const int lane = t & 63;
    const int w    = t >> 6;
    const int q    = lane & 15;         // fragment row/col index
    const int h    = lane >> 4;         // k-group
    const int r0   = blockIdx.x * 128;
    const int c0   = blockIdx.y * 128;

    // staging source pre-swizzle: lane l covers LDS row (seg*8 + l>>3), chunk l&7 (physical)
    // -> logical k-chunk = (l&7) ^ (l>>3)
    const int lrow   = lane >> 3;
    const int kschunk = (lane & 7) ^ lrow;

    f32x4 acc[4][4];
    #pragma unroll
    for (int mi = 0; mi < 4; ++mi)
        #pragma unroll
        for (int nj = 0; nj < 4; ++nj)
            #pragma unroll
            for (int r = 0; r < 4; ++r) acc[mi][nj][r] = 0.f;

    for (int k0 = 0; k0 < CK; k0 += 64) {
        #pragma unroll
        for (int i2 = 0; i2 < 4; ++i2) {
            const int seg = i2 * 4 + w;            // wave-uniform, 0..15 (8 rows each)
            const int row = seg * 8 + lrow;
            const __hip_bfloat16* gA = agg + (size_t)(r0 + row) * CK + k0 + 8 * kschunk;
            const __hip_bfloat16* gB = W   + (size_t)(c0 + row) * CK + k0 + 8 * kschunk;
            GLOAD_LDS16(gA, As + seg * 512);
            GLOAD_LDS16(gB, Bs + seg * 512);
        }
        __syncthreads();   // compiler emits vmcnt(0) drain

        #pragma unroll
        for (int kk = 0; kk < 2; ++kk) {
            bf16x8 af[4], bfr[4];
            #pragma unroll
            for (int mi = 0; mi < 4; ++mi) {
                const int row = (w >> 1) * 64 + mi * 16 + q;
                const int ch  = (kk * 4 + h) ^ (row & 7);
                af[mi] = *reinterpret_cast<const bf16x8*>(As + row * 64 + ch * 8);
            }
            #pragma unroll
            for (int nj = 0; nj < 4; ++nj) {
                const int row = (w & 1) * 64 + nj * 16 + q;
                const int ch  = (kk * 4 + h) ^ (row & 7);
                bfr[nj] = *reinterpret_cast<const bf16x8*>(Bs + row * 64 + ch * 8);
            }
            #pragma unroll
            for (int mi = 0; mi < 4; ++mi)
                #pragma unroll
                for (int nj = 0; nj < 4; ++nj)
                    acc[mi][nj] = __builtin_amdgcn_mfma_f32_16x16x32_bf16(
                        af[mi], bfr[nj], acc[mi][nj], 0, 0, 0);
        }
        __syncthreads();   // before next stage overwrites
    }

    #pragma unroll
    for (int mi = 0; mi < 4; ++mi) {
        #pragma unroll
        for (int nj = 0; nj < 4; ++nj) {
            const int col  = c0 + (w & 1) * 64 + nj * 16 + q;
            const float bias = bf[col];
            #pragma unroll
            for (int r = 0; r < 4; ++r) {
                const int row = r0 + (w >> 1) * 64 + mi * 16 + h * 4 + r;
                if (row < M)
                    out[(size_t)row * C_OUT + col] = fmaxf(acc[mi][nj][r] + bias, 0.f);
            }
        }
    }
}

extern "C" void kernel_launch(void* const* d_in, const int* in_sizes, int n_in,
                              void* d_out, int out_size, void* d_ws, size_t ws_size,
                              hipStream_t stream) {
    const float* feats  = (const float*)d_in[0];
    const float* pos    = (const float*)d_in[1];
    const int*   esrc   = (const int*)d_in[2];
    const int*   edst   = (const int*)d_in[3];
    const float* W_dir  = (const float*)d_in[4];
    const float* b_dir  = (const float*)d_in[5];
    const float* W_feat = (const float*)d_in[6];
    const float* b_feat = (const float*)d_in[7];
    float* out = (float*)d_out;

    const int N = in_sizes[1] / (BATCH * 3);
    const int E = in_sizes[2];
    const int M = BATCH * N;
    const int MBLK = (M + 127) / 128;
    const int M_pad = MBLK * 128;          // staging reads up to M_pad rows

    char* ws = (char*)d_ws;
    size_t off = 0;
    auto alignup = [&](size_t a) { off = (off + a - 1) & ~(a - 1); };

    __hip_bfloat16* agg = (__hip_bfloat16*)(ws + off); off += (size_t)M_pad * CK * sizeof(__hip_bfloat16);
    alignup(256);
    __hip_bfloat16* Wb  = (__hip_bfloat16*)(ws + off); off += (size_t)C_OUT * CK * sizeof(__hip_bfloat16);
    alignup(256);
    int* counts  = (int*)(ws + off); off += (size_t)N * sizeof(int);
    int* cursors = (int*)(ws + off); off += (size_t)N * sizeof(int);   // contiguous with counts
    alignup(256);
    int* offsets = (int*)(ws + off); off += (size_t)(N + 1) * sizeof(int);
    alignup(256);
    int* sorted_src = (int*)(ws + off); off += (size_t)E * sizeof(int);

    hipMemsetAsync(counts, 0, (size_t)2 * N * sizeof(int), stream);  // counts + cursors
    hist_kernel<<<dim3((E + 255) / 256), dim3(256), 0, stream>>>(edst, counts, E);
    scan_kernel<<<dim3(1), dim3(1024), 0, stream>>>(counts, offsets, N);
    scatter_kernel<<<dim3((E + 255) / 256), dim3(256), 0, stream>>>(edst, esrc, offsets, cursors, sorted_src, E);
    cvtw_kernel<<<dim3(C_OUT * CK / 1024), dim3(256), 0, stream>>>(W_feat, Wb);
    agg_kernel<<<dim3(N, BATCH), dim3(256), 0, stream>>>(feats, pos, sorted_src, offsets,
                                                         W_dir, b_dir, agg, N);
    gemm_kernel<<<dim3(MBLK, C_OUT / 128), dim3(256), 0, stream>>>(agg, Wb, b_feat, out, M);
}

// Round 6
// 177.106 us; speedup vs baseline: 2.2860x; 1.0986x over previous
//
#include <hip/hip_runtime.h>
#include <hip/hip_bf16.h>
#include <cstdint>
#include <cstddef>

constexpr int BATCH = 2;
constexpr int C_IN  = 64;
constexpr int CK    = 1024;   // C_IN * N_FILTERS
constexpr int C_OUT = 256;
constexpr int CHUNK = 32;     // edges staged per LDS pass (avg degree = 12)

using bf16x8 = __attribute__((ext_vector_type(8))) short;
using f32x4  = __attribute__((ext_vector_type(4))) float;

#define GLOAD_LDS16(g, s) \
    __builtin_amdgcn_global_load_lds((const __attribute__((address_space(1))) void*)(g), \
                                     (__attribute__((address_space(3))) void*)(s), 16, 0, 0)

// ---------------- CSR build ----------------
__global__ void hist_kernel(const int* __restrict__ dst, int* __restrict__ counts, int E) {
    int e = blockIdx.x * blockDim.x + threadIdx.x;
    if (e < E) atomicAdd(&counts[dst[e]], 1);
}

// 1024-thread single-block exclusive scan via wave shuffles (2 barriers/chunk)
__global__ __launch_bounds__(1024)
void scan_kernel(const int* __restrict__ counts, int* __restrict__ offsets, int n) {
    __shared__ int wsum[16];
    __shared__ int carry_s;
    const int t = threadIdx.x;
    const int lane = t & 63;
    const int w = t >> 6;
    if (t == 0) carry_s = 0;
    __syncthreads();
    const int nch = (n + 1023) >> 10;
    for (int c = 0; c < nch; ++c) {
        const int idx = (c << 10) + t;
        const int v = (idx < n) ? counts[idx] : 0;
        int x = v;
        #pragma unroll
        for (int off = 1; off < 64; off <<= 1) {
            int y = __shfl_up(x, off, 64);
            if (lane >= off) x += y;
        }
        if (lane == 63) wsum[w] = x;
        __syncthreads();
        int wpre = 0, total = 0;
        #pragma unroll
        for (int i = 0; i < 16; ++i) {
            const int s = wsum[i];
            if (i < w) wpre += s;
            total += s;
        }
        const int carry = carry_s;
        if (idx < n) offsets[idx] = carry + wpre + (x - v);   // exclusive
        __syncthreads();
        if (t == 0) carry_s = carry + total;
    }
    if (t == 0) offsets[n] = carry_s;
}

__global__ void scatter_kernel(const int* __restrict__ dst, const int* __restrict__ src,
                               const int* __restrict__ offsets,
                               int* __restrict__ cursors, int* __restrict__ sorted_src, int E) {
    int e = blockIdx.x * blockDim.x + threadIdx.x;
    if (e < E) {
        const int d = dst[e];
        const int p = atomicAdd(&cursors[d], 1);
        sorted_src[offsets[d] + p] = src[e];
    }
}

// ---------------- prep: W_feat f32->bf16  +  W_dir/b_dir pack to float4 ----------------
__global__ __launch_bounds__(256)
void prep_kernel(const float* __restrict__ Wf, __hip_bfloat16* __restrict__ Wb,
                 const float* __restrict__ W_dir, const float* __restrict__ b_dir,
                 float4* __restrict__ Wp) {
    const int id = blockIdx.x * 256 + threadIdx.x;      // grid 256 blocks -> 65536 threads
    const int i = id * 4;
    const float4 v = *reinterpret_cast<const float4*>(Wf + i);
    __hip_bfloat162 a, b;
    a.x = __float2bfloat16(v.x); a.y = __float2bfloat16(v.y);
    b.x = __float2bfloat16(v.z); b.y = __float2bfloat16(v.w);
    *reinterpret_cast<__hip_bfloat162*>(Wb + i)     = a;
    *reinterpret_cast<__hip_bfloat162*>(Wb + i + 2) = b;
    if (id < CK)
        Wp[id] = make_float4(W_dir[id * 3 + 0], W_dir[id * 3 + 1], W_dir[id * 3 + 2], b_dir[id]);
}

// ---------------- per-node edge aggregation -> bf16 agg (LDS-staged, both batches) ------
// One block per node. Thread t owns k in {2t, 2t+1, 2t+512, 2t+513}; channel c0=(2t)&63.
// Phase A: stage <=CHUNK edges' dirs + full feature rows into LDS (parallel loads).
// Phase B: pure LDS+VALU inner loop (no global latency on the critical path).
__global__ __launch_bounds__(256)
void agg_kernel(const float* __restrict__ feats, const float* __restrict__ pos,
                const int* __restrict__ sorted_src, const int* __restrict__ offsets,
                const float4* __restrict__ Wp,
                __hip_bfloat16* __restrict__ agg, int N) {
    __shared__ float  feats_s[BATCH][CHUNK][C_IN];   // 16 KB
    __shared__ float4 dir_s[BATCH][CHUNK];           // 1 KB
    __shared__ int    sh_s[CHUNK];

    const int n = blockIdx.x;
    const int t = threadIdx.x;
    const int c0 = (2 * t) & 63;

    float4 wv[4];
    wv[0] = Wp[2 * t];       wv[1] = Wp[2 * t + 1];
    wv[2] = Wp[2 * t + 512]; wv[3] = Wp[2 * t + 513];

    float cx[BATCH], cy[BATCH], cz[BATCH];
    #pragma unroll
    for (int b = 0; b < BATCH; ++b) {
        const float* pb = pos + ((size_t)b * N + n) * 3;
        cx[b] = pb[0]; cy[b] = pb[1]; cz[b] = pb[2];
    }

    float acc[BATCH][4] = {};
    const int beg = offsets[n], end = offsets[n + 1];

    for (int j0 = beg; j0 < end; j0 += CHUNK) {
        const int cnt = min(CHUNK, end - j0);
        // ---- phase A ----
        if (t < cnt) {
            const int s = sorted_src[j0 + t];
            sh_s[t] = s;
            #pragma unroll
            for (int b = 0; b < BATCH; ++b) {
                const float* ps = pos + ((size_t)b * N + s) * 3;
                dir_s[b][t] = make_float4(ps[0] - cx[b], ps[1] - cy[b], ps[2] - cz[b], 0.f);
            }
        }
        __syncthreads();    // sh_s visible
        #pragma unroll
        for (int b = 0; b < BATCH; ++b) {
            const float* fb = feats + (size_t)b * N * C_IN;
            for (int idx = t; idx < cnt * C_IN; idx += 256) {
                const int e = idx >> 6, ch = idx & 63;
                feats_s[b][e][ch] = fb[(size_t)sh_s[e] * C_IN + ch];
            }
        }
        __syncthreads();    // staged data ready
        // ---- phase B ----
        #pragma unroll
        for (int b = 0; b < BATCH; ++b) {
            for (int j = 0; j < cnt; ++j) {
                const float4 d = dir_s[b][j];                               // broadcast
                const float2 f = *reinterpret_cast<const float2*>(&feats_s[b][j][c0]);
                #pragma unroll
                for (int u = 0; u < 4; ++u) {
                    const float a = fmaxf(fmaf(d.x, wv[u].x,
                                         fmaf(d.y, wv[u].y,
                                         fmaf(d.z, wv[u].z, wv[u].w))), 0.f);
                    acc[b][u] += ((u & 1) ? f.y : f.x) * a;
                }
            }
        }
        __syncthreads();    // before next chunk overwrites LDS
    }

    // self term + store
    #pragma unroll
    for (int b = 0; b < BATCH; ++b) {
        const float2 fs = *reinterpret_cast<const float2*>(
            feats + ((size_t)b * N + n) * C_IN + c0);
        #pragma unroll
        for (int u = 0; u < 4; ++u)
            acc[b][u] += ((u & 1) ? fs.y : fs.x) * fmaxf(wv[u].w, 0.f);
        __hip_bfloat16* dst = agg + ((size_t)b * N + n) * CK;
        __hip_bfloat162 v01, v23;
        v01.x = __float2bfloat16(acc[b][0]); v01.y = __float2bfloat16(acc[b][1]);
        v23.x = __float2bfloat16(acc[b][2]); v23.y = __float2bfloat16(acc[b][3]);
        *reinterpret_cast<__hip_bfloat162*>(dst + 2 * t)       = v01;
        *reinterpret_cast<__hip_bfloat162*>(dst + 2 * t + 512) = v23;
    }
}

// ---------------- MFMA GEMM, 64x64 tile (occupancy: 1256 blocks = 4.9 waves/SIMD) -------
// BK=64, 4 waves (2x2), global_load_lds + both-sides XOR swizzle (rule 21).
__global__ __launch_bounds__(256)
void gemm_kernel(const __hip_bfloat16* __restrict__ agg, const __hip_bfloat16* __restrict__ W,
                 const float* __restrict__ bf, float* __restrict__ out, int M) {
    __shared__ __hip_bfloat16 As[64 * 64];
    __shared__ __hip_bfloat16 Bs[64 * 64];
    const int t    = threadIdx.x;
    const int lane = t & 63;
    const int w    = t >> 6;
    const int q    = lane & 15;
    const int h    = lane >> 4;
    const int r0   = blockIdx.x * 64;
    const int c0   = blockIdx.y * 64;

    const int lrow    = lane >> 3;
    const int kschunk = (lane & 7) ^ lrow;   // logical k-chunk fetched into physical chunk lane&7

    f32x4 acc[2][2];
    #pragma unroll
    for (int mi = 0; mi < 2; ++mi)
        #pragma unroll
        for (int nj = 0; nj < 2; ++nj)
            #pragma unroll
            for (int r = 0; r < 4; ++r) acc[mi][nj][r] = 0.f;

    for (int k0 = 0; k0 < CK; k0 += 64) {
        #pragma unroll
        for (int i2 = 0; i2 < 2; ++i2) {
            const int seg = i2 * 4 + w;          // 0..7, wave-uniform; 8 rows each
            const int row = seg * 8 + lrow;
            const __hip_bfloat16* gA = agg + (size_t)(r0 + row) * CK + k0 + 8 * kschunk;
            const __hip_bfloat16* gB = W   + (size_t)(c0 + row) * CK + k0 + 8 * kschunk;
            GLOAD_LDS16(gA, As + seg * 512);
            GLOAD_LDS16(gB, Bs + seg * 512);
        }
        __syncthreads();

        #pragma unroll
        for (int kk = 0; kk < 2; ++kk) {
            bf16x8 af[2], bfr[2];
            #pragma unroll
            for (int mi = 0; mi < 2; ++mi) {
                const int row = (w >> 1) * 32 + mi * 16 + q;
                const int ch  = (kk * 4 + h) ^ (row & 7);
                af[mi] = *reinterpret_cast<const bf16x8*>(As + row * 64 + ch * 8);
            }
            #pragma unroll
            for (int nj = 0; nj < 2; ++nj) {
                const int row = (w & 1) * 32 + nj * 16 + q;
                const int ch  = (kk * 4 + h) ^ (row & 7);
                bfr[nj] = *reinterpret_cast<const bf16x8*>(Bs + row * 64 + ch * 8);
            }
            #pragma unroll
            for (int mi = 0; mi < 2; ++mi)
                #pragma unroll
                for (int nj = 0; nj < 2; ++nj)
                    acc[mi][nj] = __builtin_amdgcn_mfma_f32_16x16x32_bf16(
                        af[mi], bfr[nj], acc[mi][nj], 0, 0, 0);
        }
        __syncthreads();
    }

    #pragma unroll
    for (int mi = 0; mi < 2; ++mi) {
        #pragma unroll
        for (int nj = 0; nj < 2; ++nj) {
            const int col  = c0 + (w & 1) * 32 + nj * 16 + q;
            const float bias = bf[col];
            #pragma unroll
            for (int r = 0; r < 4; ++r) {
                const int row = r0 + (w >> 1) * 32 + mi * 16 + h * 4 + r;
                if (row < M)
                    out[(size_t)row * C_OUT + col] = fmaxf(acc[mi][nj][r] + bias, 0.f);
            }
        }
    }
}

extern "C" void kernel_launch(void* const* d_in, const int* in_sizes, int n_in,
                              void* d_out, int out_size, void* d_ws, size_t ws_size,
                              hipStream_t stream) {
    const float* feats  = (const float*)d_in[0];
    const float* pos    = (const float*)d_in[1];
    const int*   esrc   = (const int*)d_in[2];
    const int*   edst   = (const int*)d_in[3];
    const float* W_dir  = (const float*)d_in[4];
    const float* b_dir  = (const float*)d_in[5];
    const float* W_feat = (const float*)d_in[6];
    const float* b_feat = (const float*)d_in[7];
    float* out = (float*)d_out;

    const int N = in_sizes[1] / (BATCH * 3);
    const int E = in_sizes[2];
    const int M = BATCH * N;
    const int MBLK = (M + 63) / 64;
    const int M_pad = MBLK * 64;           // staging reads up to M_pad rows

    char* ws = (char*)d_ws;
    size_t off = 0;
    auto alignup = [&](size_t a) { off = (off + a - 1) & ~(a - 1); };

    __hip_bfloat16* agg = (__hip_bfloat16*)(ws + off); off += (size_t)M_pad * CK * sizeof(__hip_bfloat16);
    alignup(256);
    __hip_bfloat16* Wb  = (__hip_bfloat16*)(ws + off); off += (size_t)C_OUT * CK * sizeof(__hip_bfloat16);
    alignup(256);
    float4* Wp = (float4*)(ws + off); off += (size_t)CK * sizeof(float4);
    alignup(256);
    int* counts  = (int*)(ws + off); off += (size_t)N * sizeof(int);
    int* cursors = (int*)(ws + off); off += (size_t)N * sizeof(int);   // contiguous with counts
    alignup(256);
    int* offsets = (int*)(ws + off); off += (size_t)(N + 1) * sizeof(int);
    alignup(256);
    int* sorted_src = (int*)(ws + off); off += (size_t)E * sizeof(int);

    hipMemsetAsync(counts, 0, (size_t)2 * N * sizeof(int), stream);  // counts + cursors
    hist_kernel<<<dim3((E + 255) / 256), dim3(256), 0, stream>>>(edst, counts, E);
    scan_kernel<<<dim3(1), dim3(1024), 0, stream>>>(counts, offsets, N);
    scatter_kernel<<<dim3((E + 255) / 256), dim3(256), 0, stream>>>(edst, esrc, offsets, cursors, sorted_src, E);
    prep_kernel<<<dim3(C_OUT * CK / 1024), dim3(256), 0, stream>>>(W_feat, Wb, W_dir, b_dir, Wp);
    agg_kernel<<<dim3(N), dim3(256), 0, stream>>>(feats, pos, sorted_src, offsets, Wp, agg, N);
    gemm_kernel<<<dim3(MBLK, C_OUT / 64), dim3(256), 0, stream>>>(agg, Wb, b_feat, out, M);
}